// Round 3
// baseline (262.109 us; speedup 1.0000x reference)
//
#include <hip/hip_runtime.h>
#include <hip/hip_bf16.h>
#include <math.h>

// SpatialAttention fp32 B=4,C=64,N=4096 via bf16 MFMA flash attention.
// v3: barrier-free attention. K/V/Q stored in MFMA-fragment chunk order by
// prep; attn = single-wave blocks streaming coalesced 16B frag loads from
// L2 (no LDS staging, no __syncthreads). P C->A round-trip through per-wave
// LDS (same-wave RAW, lgkmcnt only). Partials stored in raw register order
// (fully coalesced 256B stores); combine sums flat + unscrambles via LDS.

constexpr int C_ = 64;
constexpr int N_ = 4096;
constexpr float LOG2E = 1.4426950408889634f;
constexpr float MBIAS = 86.5617f;   // fixed softmax bias (logits pre-scaled by log2e)

typedef float  f4 __attribute__((ext_vector_type(4)));
typedef short  s8 __attribute__((ext_vector_type(8)));

__device__ inline unsigned short f2bf(float x) {
    union { float f; unsigned u; } a; a.f = x;
    unsigned r = a.u + 0x7FFFu + ((a.u >> 16) & 1u);   // RNE
    return (unsigned short)(r >> 16);
}
__device__ inline float bf2f(unsigned short h) {
    union { float f; unsigned u; } a; a.u = ((unsigned)h) << 16; return a.f;
}
__device__ inline uint4 pack8(const float* v) {
    uint4 r;
    r.x = (unsigned)f2bf(v[0]) | ((unsigned)f2bf(v[1]) << 16);
    r.y = (unsigned)f2bf(v[2]) | ((unsigned)f2bf(v[3]) << 16);
    r.z = (unsigned)f2bf(v[4]) | ((unsigned)f2bf(v[5]) << 16);
    r.w = (unsigned)f2bf(v[6]) | ((unsigned)f2bf(v[7]) << 16);
    return r;
}
__device__ inline void pack8_split(const float* v, uint4* hi, uint4* lo) {
    unsigned short h[8]; float rem[8];
    #pragma unroll
    for (int i = 0; i < 8; ++i) { h[i] = f2bf(v[i]); rem[i] = v[i] - bf2f(h[i]); }
    hi->x = (unsigned)h[0] | ((unsigned)h[1] << 16);
    hi->y = (unsigned)h[2] | ((unsigned)h[3] << 16);
    hi->z = (unsigned)h[4] | ((unsigned)h[5] << 16);
    hi->w = (unsigned)h[6] | ((unsigned)h[7] << 16);
    *lo = pack8(rem);
}

// ---------------- prep ----------------
// grid (64 n-tiles, B), 256 threads. Computes q,k,v for a 64n x 64o tile
// with W in LDS (transposed), then emits frag-chunk-ordered bf16 outputs.
__global__ __launch_bounds__(256) void prep_kernel(
    const float* __restrict__ x,
    const float* __restrict__ Wq, const float* __restrict__ bq,
    const float* __restrict__ Wk, const float* __restrict__ bk,
    const float* __restrict__ Wv, const float* __restrict__ bv,
    unsigned short* __restrict__ qhi, unsigned short* __restrict__ qlo,
    unsigned short* __restrict__ khi, unsigned short* __restrict__ klo,
    unsigned short* __restrict__ vv)
{
    __shared__ __align__(16) char smem[70400];
    float (*xs)[68]  = (float(*)[68])(smem);           // [c][n]
    float (*wqs)[68] = (float(*)[68])(smem + 17408);   // [c][o]
    float (*wks)[68] = (float(*)[68])(smem + 34816);
    float (*wvs)[68] = (float(*)[68])(smem + 52224);
    float* bias      = (float*)(smem + 69632);         // 3*64
    // staging aliases (valid after the post-compute barrier)
    float (*qs2)[68] = (float(*)[68])(smem);           // [i][c]
    float (*ks2)[68] = (float(*)[68])(smem + 17408);   // [j][c]
    float (*vs2)[68] = (float(*)[68])(smem + 34816);   // [c][j]

    const int t  = threadIdx.x;
    const int nt = blockIdx.x, b = blockIdx.y;
    const int n0 = nt * 64;

    // ---- phase A: load x tile + W (transposed) + bias ----
    {
        const int nl = t & 63, cb = t >> 6;
        #pragma unroll
        for (int it = 0; it < 16; ++it) {
            int c = it * 4 + cb;
            xs[c][nl] = x[((long)b * 64 + c) * N_ + n0 + nl];
        }
        #pragma unroll
        for (int kk = 0; kk < 4; ++kk) {
            int f = t * 4 + kk * 1024;       // Wq flat = o*64 + c
            int o = f >> 6, c = f & 63;
            float4 w = *(const float4*)&Wq[f];
            wqs[c+0][o] = w.x; wqs[c+1][o] = w.y; wqs[c+2][o] = w.z; wqs[c+3][o] = w.w;
            w = *(const float4*)&Wk[f];
            wks[c+0][o] = w.x; wks[c+1][o] = w.y; wks[c+2][o] = w.z; wks[c+3][o] = w.w;
            w = *(const float4*)&Wv[f];
            wvs[c+0][o] = w.x; wvs[c+1][o] = w.y; wvs[c+2][o] = w.z; wvs[c+3][o] = w.w;
        }
        if (t < 64) { bias[t] = bq[t]; bias[64 + t] = bk[t]; bias[128 + t] = bv[t]; }
    }
    __syncthreads();

    // ---- phase B: 4x4 register tile x 3 matrices ----
    const int o4 = (t & 15) * 4, n4 = (t >> 4) * 4;
    float aq[4][4], ak[4][4], av[4][4];
    #pragma unroll
    for (int oo = 0; oo < 4; ++oo)
        #pragma unroll
        for (int nn = 0; nn < 4; ++nn) {
            aq[oo][nn] = bias[o4 + oo];
            ak[oo][nn] = bias[64 + o4 + oo];
            av[oo][nn] = bias[128 + o4 + oo];
        }
    #pragma unroll 4
    for (int c = 0; c < 64; ++c) {
        f4 xv = *(const f4*)&xs[c][n4];
        f4 w1 = *(const f4*)&wqs[c][o4];
        f4 w2 = *(const f4*)&wks[c][o4];
        f4 w3 = *(const f4*)&wvs[c][o4];
        #pragma unroll
        for (int oo = 0; oo < 4; ++oo)
            #pragma unroll
            for (int nn = 0; nn < 4; ++nn) {
                aq[oo][nn] = fmaf(w1[oo], xv[nn], aq[oo][nn]);
                ak[oo][nn] = fmaf(w2[oo], xv[nn], ak[oo][nn]);
                av[oo][nn] = fmaf(w3[oo], xv[nn], av[oo][nn]);
            }
    }
    __syncthreads();

    // ---- phase C: stage to LDS in transpose-friendly layouts ----
    #pragma unroll
    for (int oo = 0; oo < 4; ++oo)
        #pragma unroll
        for (int nn = 0; nn < 4; ++nn) {
            qs2[n4 + nn][o4 + oo] = aq[oo][nn] * LOG2E;
            ks2[n4 + nn][o4 + oo] = ak[oo][nn];
            vs2[o4 + oo][n4 + nn] = av[oo][nn];
        }
    __syncthreads();

    // ---- phase D: emit frag-chunk-ordered outputs (coalesced 16B stores) ----
    const long gbase = ((long)b * 64 + nt) * 512;   // 16B-chunk index base
    #pragma unroll
    for (int half = 0; half < 2; ++half) {
        int ci = t + half * 256;
        {   // q: chunk = (m*2+ks)*64 + L ; holds q[m*16+(L&15)][ks*32+((L>>4)&3)*8 ..+7]
            int m = ci >> 7, ks = (ci >> 6) & 1, L = ci & 63;
            int row = m * 16 + (L & 15), c0 = ks * 32 + ((L >> 4) & 3) * 8;
            float tmp[8];
            *(f4*)tmp       = *(const f4*)&qs2[row][c0];
            *(f4*)(tmp + 4) = *(const f4*)&qs2[row][c0 + 4];
            uint4 hi, lo; pack8_split(tmp, &hi, &lo);
            *(uint4*)(qhi + (gbase + ci) * 8) = hi;
            *(uint4*)(qlo + (gbase + ci) * 8) = lo;
        }
        {   // k: chunk = (c>>3)*64 + j ; holds k[8c's][j]
            int cc = ci >> 6, j = ci & 63;
            float tmp[8];
            *(f4*)tmp       = *(const f4*)&ks2[j][cc * 8];
            *(f4*)(tmp + 4) = *(const f4*)&ks2[j][cc * 8 + 4];
            uint4 hi, lo; pack8_split(tmp, &hi, &lo);
            *(uint4*)(khi + (gbase + ci) * 8) = hi;
            *(uint4*)(klo + (gbase + ci) * 8) = lo;
        }
        {   // v: chunk = (j>>3)*64 + c ; holds v[c][8j's]
            int cj = ci >> 6, c = ci & 63;
            float tmp[8];
            *(f4*)tmp       = *(const f4*)&vs2[c][cj * 8];
            *(f4*)(tmp + 4) = *(const f4*)&vs2[c][cj * 8 + 4];
            *(uint4*)(vv + (gbase + ci) * 8) = pack8(tmp);
        }
    }
}

// ---------------- attention: single-wave blocks, no barriers ----------------
__global__ __launch_bounds__(64) void attn_kernel(
    const unsigned short* __restrict__ qhi, const unsigned short* __restrict__ qlo,
    const unsigned short* __restrict__ khi, const unsigned short* __restrict__ klo,
    const unsigned short* __restrict__ vv,
    float* __restrict__ Opart, float* __restrict__ lpart,
    int njt, int Bn)
{
    __shared__ __align__(16) char pst[9216];   // 64 rows x 144B (P round-trip)

    const int t  = threadIdx.x;                // lane 0..63
    const int lh = t >> 4, ll = t & 15;
    const int ib = blockIdx.x;                 // 64-row i-block 0..63
    const int jc = blockIdx.y, b = blockIdx.z;

    // Q A-frags: fully coalesced chunk loads
    s8 qh[4][2], ql[4][2];
    {
        const long qb = ((long)b * 64 + ib) * 512;
        #pragma unroll
        for (int m = 0; m < 4; ++m)
            #pragma unroll
            for (int ks = 0; ks < 2; ++ks) {
                long ch = qb + (m * 2 + ks) * 64 + t;
                qh[m][ks] = *(const s8*)(qhi + ch * 8);
                ql[m][ks] = *(const s8*)(qlo + ch * 8);
            }
    }

    f4 O[4][4];
    #pragma unroll
    for (int m = 0; m < 4; ++m)
        #pragma unroll
        for (int nn = 0; nn < 4; ++nn) O[m][nn] = (f4){0.f, 0.f, 0.f, 0.f};
    float lp[4][4];
    #pragma unroll
    for (int m = 0; m < 4; ++m)
        #pragma unroll
        for (int r = 0; r < 4; ++r) lp[m][r] = 0.f;

    const int jt0 = jc * njt;
    for (int jt = 0; jt < njt; ++jt) {
        const long kb = ((long)b * 64 + jt0 + jt) * 512;

        // ---- S = Q^T K (3-pass split bf16) + softmax + P -> pst ----
        #pragma unroll
        for (int js = 0; js < 4; ++js) {
            s8 bh[2], bl[2];
            #pragma unroll
            for (int ks = 0; ks < 2; ++ks) {
                long ch = kb + (ks * 4 + lh) * 64 + js * 16 + ll;
                bh[ks] = *(const s8*)(khi + ch * 8);
                bl[ks] = *(const s8*)(klo + ch * 8);
            }
            #pragma unroll
            for (int m = 0; m < 4; ++m) {
                f4 acc = (f4){0.f, 0.f, 0.f, 0.f};
                acc = __builtin_amdgcn_mfma_f32_16x16x32_bf16(qh[m][0], bh[0], acc, 0, 0, 0);
                acc = __builtin_amdgcn_mfma_f32_16x16x32_bf16(qh[m][1], bh[1], acc, 0, 0, 0);
                acc = __builtin_amdgcn_mfma_f32_16x16x32_bf16(qh[m][0], bl[0], acc, 0, 0, 0);
                acc = __builtin_amdgcn_mfma_f32_16x16x32_bf16(qh[m][1], bl[1], acc, 0, 0, 0);
                acc = __builtin_amdgcn_mfma_f32_16x16x32_bf16(ql[m][0], bh[0], acc, 0, 0, 0);
                acc = __builtin_amdgcn_mfma_f32_16x16x32_bf16(ql[m][1], bh[1], acc, 0, 0, 0);
                float p[4], pp[4];
                #pragma unroll
                for (int r = 0; r < 4; ++r) {
                    p[r] = exp2f(acc[r] - MBIAS);
                    lp[m][r] += p[r];
                    pp[r] = __shfl_xor(p[r], 1);
                }
                #pragma unroll
                for (int r2 = 0; r2 < 2; ++r2) {
                    int r = r2 * 2 + (ll & 1);
                    float a  = (ll & 1) ? pp[r] : p[r];
                    float c2 = (ll & 1) ? p[r] : pp[r];
                    __hip_bfloat162 hb = __float22bfloat162_rn(make_float2(a, c2));
                    unsigned pu = *(unsigned*)&hb;
                    int row  = m * 16 + lh * 4 + r;
                    int col2 = js * 16 + (ll & ~1);
                    *(unsigned*)(pst + row * 144 + col2 * 2) = pu;
                }
            }
        }

        // ---- O += P V ----
        #pragma unroll
        for (int ks = 0; ks < 2; ++ks) {
            s8 bvf[4];
            #pragma unroll
            for (int nn = 0; nn < 4; ++nn) {
                long ch = kb + (ks * 4 + lh) * 64 + nn * 16 + ll;
                bvf[nn] = *(const s8*)(vv + ch * 8);
            }
            #pragma unroll
            for (int m = 0; m < 4; ++m) {
                s8 ap = *(const s8*)(pst + (m * 16 + ll) * 144 + ks * 64 + lh * 16);
                #pragma unroll
                for (int nn = 0; nn < 4; ++nn)
                    O[m][nn] = __builtin_amdgcn_mfma_f32_16x16x32_bf16(ap, bvf[nn], O[m][nn], 0, 0, 0);
            }
        }
    }

    // ---- epilogue: l reduce + raw-order coalesced partial stores ----
    #pragma unroll
    for (int m = 0; m < 4; ++m)
        #pragma unroll
        for (int r = 0; r < 4; ++r) {
            float s = lp[m][r];
            s += __shfl_xor(s, 1); s += __shfl_xor(s, 2);
            s += __shfl_xor(s, 4); s += __shfl_xor(s, 8);
            lp[m][r] = s;
        }
    const long obase = ((long)jc * Bn + b) * 64 + ib;
    if (ll == 0) {
        #pragma unroll
        for (int m = 0; m < 4; ++m)
            #pragma unroll
            for (int r = 0; r < 4; ++r)
                lpart[obase * 64 + m * 16 + lh * 4 + r] = lp[m][r];
    }
    float* op = Opart + obase * 4096;
    #pragma unroll
    for (int m = 0; m < 4; ++m)
        #pragma unroll
        for (int nn = 0; nn < 4; ++nn)
            #pragma unroll
            for (int r = 0; r < 4; ++r)
                op[(((m * 4 + nn) * 4 + r) << 6) + t] = O[m][nn][r];
}

// ---------------- combine ----------------
__global__ __launch_bounds__(256) void combine_kernel(
    const float* __restrict__ Opart, const float* __restrict__ lpart,
    const float* __restrict__ x, const float* __restrict__ gamma_p,
    float* __restrict__ out, int js, int Bn)
{
    __shared__ float trn[64][68];   // [col=c][row=i]
    __shared__ float lsc[64];
    const int t  = threadIdx.x;
    const int ib = blockIdx.x, b = blockIdx.y;
    const float g = gamma_p[0];

    f4 acc[4];
    #pragma unroll
    for (int kk = 0; kk < 4; ++kk) acc[kk] = (f4){0.f, 0.f, 0.f, 0.f};
    for (int jc = 0; jc < js; ++jc) {
        const float* base = Opart + (((long)jc * Bn + b) * 64 + ib) * 4096;
        #pragma unroll
        for (int kk = 0; kk < 4; ++kk)
            acc[kk] += *(const f4*)(base + (t + kk * 256) * 4);
    }
    if (t < 64) {
        float ls = 0.f;
        for (int jc = 0; jc < js; ++jc)
            ls += lpart[(((long)jc * Bn + b) * 64 + ib) * 64 + t];
        lsc[t] = g / ls;
    }
    #pragma unroll
    for (int kk = 0; kk < 4; ++kk)
        #pragma unroll
        for (int e = 0; e < 4; ++e) {
            int flat = (t + kk * 256) * 4 + e;
            int idx = flat >> 6, L = flat & 63;
            int r = idx & 3, nn = (idx >> 2) & 3, m = idx >> 4;
            int row = m * 16 + (L >> 4) * 4 + r, col = nn * 16 + (L & 15);
            trn[col][row] = acc[kk][e];
        }
    __syncthreads();

    const int cl = t >> 2, nq = (t & 3) * 16;
    const long ob = ((long)b * 64 + cl) * N_ + ib * 64 + nq;
    #pragma unroll
    for (int qq = 0; qq < 4; ++qq) {
        float4 xr = *(const float4*)&x[ob + qq * 4];
        float4 rr;
        rr.x = trn[cl][nq + qq*4 + 0] * lsc[nq + qq*4 + 0] + xr.x;
        rr.y = trn[cl][nq + qq*4 + 1] * lsc[nq + qq*4 + 1] + xr.y;
        rr.z = trn[cl][nq + qq*4 + 2] * lsc[nq + qq*4 + 2] + xr.z;
        rr.w = trn[cl][nq + qq*4 + 3] * lsc[nq + qq*4 + 3] + xr.w;
        *(float4*)&out[ob + qq * 4] = rr;
    }
}

extern "C" void kernel_launch(void* const* d_in, const int* in_sizes, int n_in,
                              void* d_out, int out_size, void* d_ws, size_t ws_size,
                              hipStream_t stream) {
    const float* x  = (const float*)d_in[0];
    const float* Wq = (const float*)d_in[1];
    const float* bq = (const float*)d_in[2];
    const float* Wk = (const float*)d_in[3];
    const float* bk = (const float*)d_in[4];
    const float* Wv = (const float*)d_in[5];
    const float* bv = (const float*)d_in[6];
    const float* gm = (const float*)d_in[7];
    float* out = (float*)d_out;

    const int B = in_sizes[0] / (C_ * N_);            // 4
    const size_t per = (size_t)B * N_ * C_;           // 1M elements
    char* w = (char*)d_ws;
    unsigned short* qhi = (unsigned short*)w;
    unsigned short* qlo = qhi + per;
    unsigned short* khi = qlo + per;
    unsigned short* klo = khi + per;
    unsigned short* vv  = klo + per;                  // 10 MB
    size_t base = 5 * per * sizeof(unsigned short);

    int js = 8;
    while (js > 1) {
        size_t need = base + (size_t)js *
            ((size_t)B * 64 * 4096 * 4 + (size_t)B * 64 * 64 * 4);
        if (need <= ws_size) break;
        js >>= 1;
    }
    float* Opart = (float*)(w + base);
    float* lpart = (float*)(w + base + (size_t)js * (size_t)B * 64 * 4096 * 4);

    prep_kernel<<<dim3(64, B), 256, 0, stream>>>(x, Wq, bq, Wk, bk, Wv, bv,
                                                 qhi, qlo, khi, klo, vv);
    attn_kernel<<<dim3(64, js, B), 64, 0, stream>>>(qhi, qlo, khi, klo, vv,
                                                    Opart, lpart, 64 / js, B);
    combine_kernel<<<dim3(64, B), 256, 0, stream>>>(Opart, lpart, x, gm, out, js, B);
}